// Round 14
// baseline (105.648 us; speedup 1.0000x reference)
//
#include <hip/hip_runtime.h>
#include <hip/hip_bf16.h>
#include <stdint.h>

#define B_N 8192
#define D_N 1024
#define K_N 8
#define H_N 2048

#define BM 256
#define BN 256
#define BK 64
#define GRID_MT 40
// LDS map (bytes): 2 K-tile buffers of 64 KB, each split into 4 16KB K-regions:
//   buf base = (t&1)*65536;  Ak0 @+0, Ak1 @+16384, Bk0 @+32768, Bk1 @+49152
//   ro=131072(1024) pll=132096(4096)  total 136192 (<=163840)
#define REGB 16384
#define BUFB 65536
#define BOFF 32768
#define RO_OFF 131072
#define PLL_OFF 132096
#define GEMM_LDS 136192

typedef unsigned int u32;
typedef unsigned short u16;
typedef __attribute__((ext_vector_type(8))) short short8;
typedef __attribute__((ext_vector_type(4))) float float4v;

struct __align__(8) us4 { u16 x, y, z, w; };

__device__ __forceinline__ u16 f2bf(float f) {
    union { float f; u32 u; } v; v.f = f;
    u32 u = v.u;
    u32 r = (u + 0x7fffu + ((u >> 16) & 1u)) >> 16;
    return (u16)r;
}

__device__ __forceinline__ float fast_tanh(float x) {
    float t = __expf(2.0f * x);
    return 1.0f - 2.0f * __builtin_amdgcn_rcpf(t + 1.0f);
}

__device__ __forceinline__ void async_copy16(void* lds, const void* g) {
    __builtin_amdgcn_global_load_lds(
        (const __attribute__((address_space(1))) void*)g,
        (__attribute__((address_space(3))) void*)lds, 16, 0, 0);
}

// ---------------- fused prep: w1t transpose + routing, interleaved 2:1 -----------
__global__ void prep_kernel(const float* __restrict__ w1, u16* __restrict__ w1t,
                            u32* __restrict__ counts,
                            const float* __restrict__ x, const float* __restrict__ cent,
                            const float* __restrict__ b2, u16* __restrict__ xbf,
                            int* __restrict__ cluster, float* __restrict__ out) {
    __shared__ float ts[64][65];
    int tid = threadIdx.x;
    int bid = (int)blockIdx.x;
    int m3 = bid % 3;

    if (m3 == 2) {
        int rb = bid / 3;                 // 0..2047
        int wave = tid >> 6, lane = tid & 63;
        int b = rb * 4 + wave;
        const float* xr = x + (size_t)b * D_N;

        float4 xv[4];
#pragma unroll
        for (int i = 0; i < 4; ++i)
            xv[i] = *(const float4*)(xr + i * 256 + lane * 4);

#pragma unroll
        for (int i = 0; i < 4; ++i) {
            us4 o;
            o.x = f2bf(xv[i].x); o.y = f2bf(xv[i].y);
            o.z = f2bf(xv[i].z); o.w = f2bf(xv[i].w);
            *(us4*)(xbf + (size_t)b * D_N + i * 256 + lane * 4) = o;
        }

        double acc[K_N];
#pragma unroll
        for (int k = 0; k < K_N; ++k) {
            const float* cr = cent + k * D_N;
            double s = 0.0;
#pragma unroll
            for (int i = 0; i < 4; ++i) {
                float4 cv = *(const float4*)(cr + i * 256 + lane * 4);
                double d0 = (double)xv[i].x - (double)cv.x; s += d0 * d0;
                double d1 = (double)xv[i].y - (double)cv.y; s += d1 * d1;
                double d2 = (double)xv[i].z - (double)cv.z; s += d2 * d2;
                double d3 = (double)xv[i].w - (double)cv.w; s += d3 * d3;
            }
            acc[k] = s;
        }
#pragma unroll
        for (int k = 0; k < K_N; ++k) {
            double v = acc[k];
            for (int off = 32; off; off >>= 1) v += __shfl_down(v, off);
            acc[k] = v;
        }
        if (lane == 0) {
            int best = 0; double bv = acc[0];
#pragma unroll
            for (int k = 1; k < K_N; ++k)
                if (acc[k] < bv) { bv = acc[k]; best = k; }
            cluster[b] = best;
            out[b] = b2[best];   // base value; gemm atomically adds partials
        }
    } else {
        int wi = (bid / 3) * 2 + m3;      // 0..4095, bijective
        if (wi == 0 && tid < K_N) counts[tid * 32] = 0;
        int hb = wi & 31, db = (wi >> 5) & 15, k = wi >> 9;
        int h0 = hb * 64, d0 = db * 64;
        const float* src = w1 + ((size_t)k * D_N + d0) * H_N + h0;
#pragma unroll
        for (int i = 0; i < 4; ++i) {
            int q = i * 256 + tid;
            int r = q >> 4, c4 = (q & 15) * 4;
            float4 v = *(const float4*)(src + (size_t)r * H_N + c4);
            ts[c4 + 0][r] = v.x; ts[c4 + 1][r] = v.y;
            ts[c4 + 2][r] = v.z; ts[c4 + 3][r] = v.w;
        }
        __syncthreads();
        u16* dst = w1t + ((size_t)k * H_N + h0) * D_N + d0;
#pragma unroll
        for (int i = 0; i < 4; ++i) {
            int q = i * 256 + tid;
            int hr = q >> 4, d4 = (q & 15) * 4;
            us4 o;
            o.x = f2bf(ts[hr][d4 + 0]); o.y = f2bf(ts[hr][d4 + 1]);
            o.z = f2bf(ts[hr][d4 + 2]); o.w = f2bf(ts[hr][d4 + 3]);
            *(us4*)(dst + (size_t)hr * D_N + d4) = o;
        }
    }
}

// ---------------- parallel binning: 32 blocks, ballot-rank + block reserve ------
__global__ void scatter_kernel(const int* __restrict__ cluster,
                               u32* __restrict__ counts,
                               u32* __restrict__ idxl) {
    __shared__ u32 wcnt[4][K_N];
    __shared__ u32 gb[K_N];
    int tid = threadIdx.x;
    int b = blockIdx.x * 256 + tid;
    int lane = tid & 63, wid = tid >> 6;
    int cl = cluster[b];
    unsigned long long lower = (1ull << lane) - 1ull;
    u32 rank = 0;
#pragma unroll
    for (int k = 0; k < K_N; ++k) {
        unsigned long long mk = __ballot(cl == k);
        if (k == cl) rank = (u32)__popcll(mk & lower);
        if (lane == 0) wcnt[wid][k] = (u32)__popcll(mk);
    }
    __syncthreads();
    if (tid < K_N) {
        u32 tot = wcnt[0][tid] + wcnt[1][tid] + wcnt[2][tid] + wcnt[3][tid];
        gb[tid] = atomicAdd(&counts[tid * 32], tot);
    }
    __syncthreads();
    u32 woff = 0;
    if (wid > 0) woff += wcnt[0][cl];
    if (wid > 1) woff += wcnt[1][cl];
    if (wid > 2) woff += wcnt[2][cl];
    idxl[(size_t)cl * B_N + gb[cl] + woff + rank] = (u32)b;
}

// ---------------- grouped fused GEMM: 256x256 tile, K-region counted pipeline ----
// T4 applied correctly for the first time: each K-tile staged as 4 16KB regions
// {Ak0,Bk0,Ak1,Bk1} (2 ops/thread each, uniform across waves). P0/P1 consume only
// {Ak0,Bk0}; P2/P3 only {Ak1,Bk1} -> gates are COUNTED vmcnt(4): every region gets
// 4 phases (~3100cy) of flight and the VMEM pipe NEVER drains to 0 in the main
// loop (m218 lever). Region rows are 64B -> R1/R7's verified paired-row swizzle
// (0 conflicts) and R7's verified fragment-offset formula reused verbatim.
// Wave tile 128x64, acc[8][4]=128 regs. Numerics: identical K-ascending order.
__global__ __launch_bounds__(512, 2) void gemm_kernel(
                            const u16* __restrict__ xbf,
                            const u16* __restrict__ w1t,
                            const float* __restrict__ b1,
                            const float* __restrict__ w2,
                            const u32* __restrict__ idxl,
                            const u32* __restrict__ counts,
                            float* __restrict__ out) {
    extern __shared__ char lds[];
    // derive (k, mt) from counts — prefix scan (handles imbalanced counts)
    int tix = (int)blockIdx.y;
    int k = -1, mt = 0, ntile = 0;
#pragma unroll
    for (int kk = 0; kk < K_N; ++kk) {
        int c = (int)counts[kk * 32];
        int t = (c + BM - 1) / BM;
        if (tix >= ntile && tix < ntile + t) { k = kk; mt = tix - ntile; }
        ntile += t;
    }
    if (k < 0) return;
    int cnt = (int)counts[k * 32];
    int nc = (int)blockIdx.x;            // nc == linear%8 (XCD-affine B slice)
    int rows = cnt - mt * BM; if (rows > BM) rows = BM;
    int tid = threadIdx.x;
    int lane = tid & 63, w = tid >> 6;
    int wm = w >> 2, wn = w & 3;
    int wmbase = wm * 128;
    int h0 = nc * BN;
    int l15 = lane & 15, l4 = lane >> 4;

    u32* ro = (u32*)(lds + RO_OFF);
    float* pll = (float*)(lds + PLL_OFF);

    if (tid < BM) {
        int m = mt * BM + tid;
        int mm = m < cnt ? m : cnt - 1;
        ro[tid] = idxl[(size_t)k * B_N + mm] * (u32)(D_N * 2);
    }
    __syncthreads();

    // staging source offsets, paired-row layout (R1/R7 verified):
    // chunk c: pair p=c>>3, u=(c&7)^(p&7) -> row=2p+(u>>2), kchunk=u&3
    u32 srcA[2], srcB[2];
#pragma unroll
    for (int i = 0; i < 2; ++i) {
        int c = i * 512 + tid;
        int p = c >> 3, u = (c & 7) ^ (p & 7);
        int row = 2 * p + (u >> 2);
        srcA[i] = ro[row] + (u32)((u & 3) << 4);
        srcB[i] = ((u32)(k * H_N + h0 + row) << 11) + (u32)((u & 3) << 4);
    }
    const char* xb = (const char*)xbf;
    const char* wb = (const char*)w1t;

    // fragment offset within a region (R7 verified): row = rbase + l15, kchunk = l4
    u32 frOff = (u32)(((l15 >> 1) << 7) |
                      (((((l15 & 1) << 2) | l4) ^ ((l15 >> 1) & 7)) << 4));
    u32 aW = (u32)(wmbase * 64) + frOff;          // + kkh*REGB + mf*1024
    u32 bW = (u32)(BOFF + wn * 4096) + frOff;     // + kkh*REGB + nf*1024

    float4v acc[8][4];
#pragma unroll
    for (int mf = 0; mf < 8; ++mf)
#pragma unroll
        for (int nf = 0; nf < 4; ++nf)
            acc[mf][nf] = (float4v){0.f, 0.f, 0.f, 0.f};

    auto stA = [&](int tt, int kkh) {
        char* dst = lds + (tt & 1) * BUFB + kkh * REGB;
        u32 so = (u32)(kkh * 64 + (tt << 7));
        async_copy16(dst + tid * 16,        xb + srcA[0] + so);
        async_copy16(dst + 8192 + tid * 16, xb + srcA[1] + so);
    };
    auto stB = [&](int tt, int kkh) {
        char* dst = lds + (tt & 1) * BUFB + BOFF + kkh * REGB;
        u32 so = (u32)(kkh * 64 + (tt << 7));
        async_copy16(dst + tid * 16,        wb + srcB[0] + so);
        async_copy16(dst + 8192 + tid * 16, wb + srcB[1] + so);
    };

#define BAR() do { asm volatile("" ::: "memory"); __builtin_amdgcn_s_barrier(); \
                   asm volatile("" ::: "memory"); } while (0)
#define MFMA_PHASE(MFB, BREG)                                                    \
    do {                                                                         \
        __builtin_amdgcn_s_setprio(1);                                           \
        _Pragma("unroll")                                                        \
        for (int i_ = 0; i_ < 4; ++i_) {                                         \
            if (wmbase + ((MFB) + i_) * 16 < rows) {                             \
                _Pragma("unroll")                                                \
                for (int nf_ = 0; nf_ < 4; ++nf_)                                \
                    acc[(MFB) + i_][nf_] = __builtin_amdgcn_mfma_f32_16x16x32_bf16( \
                        a[i_], BREG[nf_], acc[(MFB) + i_][nf_], 0, 0, 0);        \
            }                                                                    \
        }                                                                        \
        __builtin_amdgcn_s_setprio(0);                                           \
    } while (0)

    // prologue: stage tile 0's regions in FIFO order Ak0,Bk0,Ak1,Bk1 (8 ops)
    stA(0, 0); stB(0, 0); stA(0, 1); stB(0, 1);

    for (int t = 0; t < 16; ++t) {
        const char* bufc = lds + (t & 1) * BUFB;
        bool pre = (t < 15);
        short8 a[4], bC[4];

        // ---- P0 gate: Ak0(t),Bk0(t) are the 4 oldest of <=8 outstanding
        asm volatile("s_waitcnt vmcnt(4)" ::: "memory");
        BAR();
#pragma unroll
        for (int nf = 0; nf < 4; ++nf)
            bC[nf] = *(const short8*)(bufc + bW + nf * 1024);
#pragma unroll
        for (int i = 0; i < 4; ++i)
            a[i] = *(const short8*)(bufc + aW + i * 1024);
        if (pre) stA(t + 1, 0);
        BAR();
        MFMA_PHASE(0, bC);

        // ---- P1: A(kk0, mf4-7); stage Bk0(t+1)
        BAR();
#pragma unroll
        for (int i = 0; i < 4; ++i)
            a[i] = *(const short8*)(bufc + aW + (4 + i) * 1024);
        if (pre) stB(t + 1, 0);
        BAR();
        MFMA_PHASE(4, bC);

        // ---- P2 gate: Ak1(t),Bk1(t) are the 4 oldest (last tile: drain all)
        if (t < 15) asm volatile("s_waitcnt vmcnt(4)" ::: "memory");
        else        asm volatile("s_waitcnt vmcnt(0)" ::: "memory");
        BAR();
#pragma unroll
        for (int nf = 0; nf < 4; ++nf)
            bC[nf] = *(const short8*)(bufc + bW + REGB + nf * 1024);
#pragma unroll
        for (int i = 0; i < 4; ++i)
            a[i] = *(const short8*)(bufc + aW + REGB + i * 1024);
        if (pre) stA(t + 1, 1);
        BAR();
        MFMA_PHASE(0, bC);

        // ---- P3: A(kk1, mf4-7); stage Bk1(t+1)
        BAR();
#pragma unroll
        for (int i = 0; i < 4; ++i)
            a[i] = *(const short8*)(bufc + aW + REGB + (4 + i) * 1024);
        if (pre) stB(t + 1, 1);
        BAR();
        MFMA_PHASE(4, bC);
    }

#undef BAR
#undef MFMA_PHASE

    // epilogue: tanh + W2 weighted row-sum
    float w2v[4], b1v[4];
#pragma unroll
    for (int nf = 0; nf < 4; ++nf) {
        int h = h0 + wn * 64 + nf * 16 + l15;
        w2v[nf] = w2[k * H_N + h];
        b1v[nf] = b1[k * H_N + h];
    }
#pragma unroll
    for (int mf = 0; mf < 8; ++mf) {
        float rs[4] = {0.f, 0.f, 0.f, 0.f};
#pragma unroll
        for (int nf = 0; nf < 4; ++nf) {
#pragma unroll
            for (int r = 0; r < 4; ++r)
                rs[r] += fast_tanh(acc[mf][nf][r] + b1v[nf]) * w2v[nf];
        }
#pragma unroll
        for (int r = 0; r < 4; ++r) {
            float v = rs[r];
            v += __shfl_xor(v, 8);
            v += __shfl_xor(v, 4);
            v += __shfl_xor(v, 2);
            v += __shfl_xor(v, 1);
            if (l15 == 0) pll[wn * 256 + wmbase + mf * 16 + l4 * 4 + r] = v;
        }
    }
    __syncthreads();
    if (tid < BM) {
        int m = mt * BM + tid;
        if (m < cnt) {
            u32 b = idxl[(size_t)k * B_N + m];
            atomicAdd(&out[b], pll[tid] + pll[256 + tid] + pll[512 + tid] + pll[768 + tid]);
        }
    }
}

extern "C" void kernel_launch(void* const* d_in, const int* in_sizes, int n_in,
                              void* d_out, int out_size, void* d_ws, size_t ws_size,
                              hipStream_t stream) {
    const float* x    = (const float*)d_in[0];
    const float* cent = (const float*)d_in[1];
    const float* W1   = (const float*)d_in[2];
    const float* b1   = (const float*)d_in[3];
    const float* W2   = (const float*)d_in[4];
    const float* b2   = (const float*)d_in[5];
    float* out = (float*)d_out;

    char* ws = (char*)d_ws;
    u16* xbf     = (u16*)(ws + 0);                 // 16 MB
    u16* w1t     = (u16*)(ws + 16777216);          // 32 MB
    u32* counts  = (u32*)(ws + 50331648);          // 8 strided u32 (1 KB pad)
    int* cluster = (int*)(ws + 50332672);          // 32 KB
    u32* idxl    = (u32*)(ws + 50365440);          // 256 KB

    (void)hipFuncSetAttribute((const void*)gemm_kernel,
                              hipFuncAttributeMaxDynamicSharedMemorySize, GEMM_LDS);

    // 3 dispatches: prep (fused w1t + route; zeroes counts) -> scatter -> gemm.
    hipLaunchKernelGGL(prep_kernel, dim3(6144), dim3(256), 0, stream,
                       W1, w1t, counts, x, cent, b2, xbf, cluster, out);
    hipLaunchKernelGGL(scatter_kernel, dim3(32), dim3(256), 0, stream,
                       cluster, counts, idxl);
    hipLaunchKernelGGL(gemm_kernel, dim3(8, GRID_MT), dim3(512), GEMM_LDS, stream,
                       xbf, w1t, b1, W2, idxl, counts, out);
}

// Round 15
// 81.566 us; speedup vs baseline: 1.2952x; 1.2952x over previous
//
#include <hip/hip_runtime.h>
#include <hip/hip_bf16.h>
#include <stdint.h>

#define B_N 8192
#define D_N 1024
#define K_N 8
#define H_N 2048

#define BM 320
#define BN 256
#define BK 64
#define GRID_MT 34
// LDS map (bytes): 2 K-step buffers of (A 40960 + B 32768) = 73728:
//   buf0=0 buf1=73728 (end 147456)
//   ro=147456(1280) pll=148736(5120)  total 153856 (<=163840)
#define ABYTES 40960
#define BUFSZ 73728
#define RO_OFF 147456
#define PLL_OFF 148736
#define GEMM_LDS 153856

typedef unsigned int u32;
typedef unsigned short u16;
typedef __attribute__((ext_vector_type(8))) short short8;
typedef __attribute__((ext_vector_type(4))) float float4v;

struct __align__(8) us4 { u16 x, y, z, w; };

__device__ __forceinline__ u16 f2bf(float f) {
    union { float f; u32 u; } v; v.f = f;
    u32 u = v.u;
    u32 r = (u + 0x7fffu + ((u >> 16) & 1u)) >> 16;
    return (u16)r;
}

__device__ __forceinline__ float fast_tanh(float x) {
    float t = __expf(2.0f * x);
    return 1.0f - 2.0f * __builtin_amdgcn_rcpf(t + 1.0f);
}

__device__ __forceinline__ void async_copy16(void* lds, const void* g) {
    __builtin_amdgcn_global_load_lds(
        (const __attribute__((address_space(1))) void*)g,
        (__attribute__((address_space(3))) void*)lds, 16, 0, 0);
}

// ---------------- fused prep: w1t transpose + routing, interleaved 2:1 -----------
__global__ void prep_kernel(const float* __restrict__ w1, u16* __restrict__ w1t,
                            u32* __restrict__ counts,
                            const float* __restrict__ x, const float* __restrict__ cent,
                            const float* __restrict__ b2, u16* __restrict__ xbf,
                            int* __restrict__ cluster, float* __restrict__ out) {
    __shared__ float ts[64][65];
    int tid = threadIdx.x;
    int bid = (int)blockIdx.x;
    int m3 = bid % 3;

    if (m3 == 2) {
        int rb = bid / 3;                 // 0..2047
        int wave = tid >> 6, lane = tid & 63;
        int b = rb * 4 + wave;
        const float* xr = x + (size_t)b * D_N;

        float4 xv[4];
#pragma unroll
        for (int i = 0; i < 4; ++i)
            xv[i] = *(const float4*)(xr + i * 256 + lane * 4);

#pragma unroll
        for (int i = 0; i < 4; ++i) {
            us4 o;
            o.x = f2bf(xv[i].x); o.y = f2bf(xv[i].y);
            o.z = f2bf(xv[i].z); o.w = f2bf(xv[i].w);
            *(us4*)(xbf + (size_t)b * D_N + i * 256 + lane * 4) = o;
        }

        double acc[K_N];
#pragma unroll
        for (int k = 0; k < K_N; ++k) {
            const float* cr = cent + k * D_N;
            double s = 0.0;
#pragma unroll
            for (int i = 0; i < 4; ++i) {
                float4 cv = *(const float4*)(cr + i * 256 + lane * 4);
                double d0 = (double)xv[i].x - (double)cv.x; s += d0 * d0;
                double d1 = (double)xv[i].y - (double)cv.y; s += d1 * d1;
                double d2 = (double)xv[i].z - (double)cv.z; s += d2 * d2;
                double d3 = (double)xv[i].w - (double)cv.w; s += d3 * d3;
            }
            acc[k] = s;
        }
#pragma unroll
        for (int k = 0; k < K_N; ++k) {
            double v = acc[k];
            for (int off = 32; off; off >>= 1) v += __shfl_down(v, off);
            acc[k] = v;
        }
        if (lane == 0) {
            int best = 0; double bv = acc[0];
#pragma unroll
            for (int k = 1; k < K_N; ++k)
                if (acc[k] < bv) { bv = acc[k]; best = k; }
            cluster[b] = best;
            out[b] = b2[best];   // base value; gemm atomically adds partials
        }
    } else {
        int wi = (bid / 3) * 2 + m3;      // 0..4095, bijective
        if (wi == 0 && tid < K_N) counts[tid * 32] = 0;
        int hb = wi & 31, db = (wi >> 5) & 15, k = wi >> 9;
        int h0 = hb * 64, d0 = db * 64;
        const float* src = w1 + ((size_t)k * D_N + d0) * H_N + h0;
#pragma unroll
        for (int i = 0; i < 4; ++i) {
            int q = i * 256 + tid;
            int r = q >> 4, c4 = (q & 15) * 4;
            float4 v = *(const float4*)(src + (size_t)r * H_N + c4);
            ts[c4 + 0][r] = v.x; ts[c4 + 1][r] = v.y;
            ts[c4 + 2][r] = v.z; ts[c4 + 3][r] = v.w;
        }
        __syncthreads();
        u16* dst = w1t + ((size_t)k * H_N + h0) * D_N + d0;
#pragma unroll
        for (int i = 0; i < 4; ++i) {
            int q = i * 256 + tid;
            int hr = q >> 4, d4 = (q & 15) * 4;
            us4 o;
            o.x = f2bf(ts[hr][d4 + 0]); o.y = f2bf(ts[hr][d4 + 1]);
            o.z = f2bf(ts[hr][d4 + 2]); o.w = f2bf(ts[hr][d4 + 3]);
            *(us4*)(dst + (size_t)hr * D_N + d4) = o;
        }
    }
}

// ---------------- parallel binning: 32 blocks, ballot-rank + block reserve ------
__global__ void scatter_kernel(const int* __restrict__ cluster,
                               u32* __restrict__ counts,
                               u32* __restrict__ idxl) {
    __shared__ u32 wcnt[4][K_N];
    __shared__ u32 gb[K_N];
    int tid = threadIdx.x;
    int b = blockIdx.x * 256 + tid;
    int lane = tid & 63, wid = tid >> 6;
    int cl = cluster[b];
    unsigned long long lower = (1ull << lane) - 1ull;
    u32 rank = 0;
#pragma unroll
    for (int k = 0; k < K_N; ++k) {
        unsigned long long mk = __ballot(cl == k);
        if (k == cl) rank = (u32)__popcll(mk & lower);
        if (lane == 0) wcnt[wid][k] = (u32)__popcll(mk);
    }
    __syncthreads();
    if (tid < K_N) {
        u32 tot = wcnt[0][tid] + wcnt[1][tid] + wcnt[2][tid] + wcnt[3][tid];
        gb[tid] = atomicAdd(&counts[tid * 32], tot);
    }
    __syncthreads();
    u32 woff = 0;
    if (wid > 0) woff += wcnt[0][cl];
    if (wid > 1) woff += wcnt[1][cl];
    if (wid > 2) woff += wcnt[2][cl];
    idxl[(size_t)cl * B_N + gb[cl] + woff + rank] = (u32)b;
}

// ---------------- grouped fused GEMM: 320x256 tile, BK=64, SINGLE-BARRIER step --
// Champion schedule with ONE isolated change: the K-step's 8 barriers collapse
// to 1 (the vmcnt(0)+BAR buffer-ready gate). Correctness audit: the only
// cross-wave hazard is staging into buf (t+1)&1 overwriting data read in step
// t-1 -- but those ds_reads are forced complete (compiler lgkm before dependent
// MFMAs) before each wave reaches step t's gate, and staging is issued after
// the gate. The other 7 barriers only enforced the phase convoy (the ~30us
// cost term: 128 block-wide syncs). Reads/staging/accumulation order unchanged
// -> bit-identical numerics.
__global__ __launch_bounds__(512, 2) void gemm_kernel(
                            const u16* __restrict__ xbf,
                            const u16* __restrict__ w1t,
                            const float* __restrict__ b1,
                            const float* __restrict__ w2,
                            const u32* __restrict__ idxl,
                            const u32* __restrict__ counts,
                            float* __restrict__ out) {
    extern __shared__ char lds[];
    // derive (k, mt) from counts — prefix scan (handles imbalanced counts)
    int tix = (int)blockIdx.y;
    int k = -1, mt = 0, ntile = 0;
#pragma unroll
    for (int kk = 0; kk < K_N; ++kk) {
        int c = (int)counts[kk * 32];
        int t = (c + BM - 1) / BM;
        if (tix >= ntile && tix < ntile + t) { k = kk; mt = tix - ntile; }
        ntile += t;
    }
    if (k < 0) return;
    int cnt = (int)counts[k * 32];
    int nc = (int)blockIdx.x;            // nc == linear%8
    int rows = cnt - mt * BM; if (rows > BM) rows = BM;
    int tid = threadIdx.x;
    int lane = tid & 63, w = tid >> 6;
    int wm = w >> 2, wn = w & 3;
    int wmbase = wm * 160;
    int h0 = nc * BN;
    int l15 = lane & 15, l4 = lane >> 4;

    u32* ro = (u32*)(lds + RO_OFF);
    float* pll = (float*)(lds + PLL_OFF);

    if (tid < BM) {
        int m = mt * BM + tid;
        int mm = m < cnt ? m : cnt - 1;
        ro[tid] = idxl[(size_t)k * B_N + mm] * (u32)(D_N * 2);
    }
    __syncthreads();

    // staging source offsets (pre-swizzled: linear LDS dest + swizzled read)
    u32 srcA[5], srcB[4];
#pragma unroll
    for (int i = 0; i < 5; ++i) {
        int c = i * 512 + tid; int r = c >> 3, j = c & 7;
        srcA[i] = ro[r] + ((u32)(j ^ (r & 7)) << 4);
    }
#pragma unroll
    for (int i = 0; i < 4; ++i) {
        int c = i * 512 + tid; int r = c >> 3, j = c & 7;
        srcB[i] = ((u32)(k * H_N + h0 + r) << 11) + ((u32)(j ^ (r & 7)) << 4);
    }
    const char* xb = (const char*)xbf;
    const char* wb = (const char*)w1t;

    // per-lane fragment base offsets (chunk = (kk*4+l4) ^ (row&7); row&7 == l15&7)
    int swz = l15 & 7;
    u32 aB0 = (u32)((wmbase + l15) * 128 + (((0 + l4) ^ swz) << 4));
    u32 aB1 = (u32)((wmbase + l15) * 128 + (((4 + l4) ^ swz) << 4));
    u32 bB0 = (u32)(ABYTES + (wn * 64 + l15) * 128 + (((0 + l4) ^ swz) << 4));
    u32 bB1 = (u32)(ABYTES + (wn * 64 + l15) * 128 + (((4 + l4) ^ swz) << 4));

    float4v acc[10][4];
#pragma unroll
    for (int mf = 0; mf < 10; ++mf)
#pragma unroll
        for (int nf = 0; nf < 4; ++nf)
            acc[mf][nf] = (float4v){0.f, 0.f, 0.f, 0.f};

#define STA(BUF, I, D) async_copy16((BUF) + (I) * 8192 + w * 1024, xb + srcA[I] + (D))
#define STB(BUF, I, D) async_copy16((BUF) + ABYTES + (I) * 8192 + w * 1024, wb + srcB[I] + (D))
#define BAR() do { asm volatile("" ::: "memory"); __builtin_amdgcn_s_barrier(); \
                   asm volatile("" ::: "memory"); } while (0)

    // prologue: stage K-step 0 into buf 0 (drained by the gate at t=0)
    {
        char* Bp = lds;
        STA(Bp, 0, 0); STA(Bp, 1, 0); STA(Bp, 2, 0); STA(Bp, 3, 0); STA(Bp, 4, 0);
        STB(Bp, 0, 0); STB(Bp, 1, 0); STB(Bp, 2, 0); STB(Bp, 3, 0);
    }

    for (int t = 0; t < 16; ++t) {
        const char* Acur = lds + (t & 1) * BUFSZ;
        char* Bnx = lds + ((t + 1) & 1) * BUFSZ;
        u32 d = (u32)((t + 1) << 7);
        bool pre = (t < 15);
        short8 a[10], bC[4];

        // ---- single gate per K-step: buffer t landed; all waves' t-1 reads done
        asm volatile("s_waitcnt vmcnt(0)" ::: "memory");
        BAR();

        // kk0: reads, then issue ALL staging for t+1 (max flight), then 40 MFMA
#pragma unroll
        for (int nf = 0; nf < 4; ++nf)
            bC[nf] = *(const short8*)(Acur + bB0 + nf * 2048);
#pragma unroll
        for (int i = 0; i < 10; ++i)
            a[i] = *(const short8*)(Acur + aB0 + i * 2048);
        if (pre) {
            STB(Bnx, 0, d); STB(Bnx, 1, d); STB(Bnx, 2, d); STB(Bnx, 3, d);
            STA(Bnx, 0, d); STA(Bnx, 1, d); STA(Bnx, 2, d); STA(Bnx, 3, d); STA(Bnx, 4, d);
        }
        __builtin_amdgcn_s_setprio(1);
#pragma unroll
        for (int mf = 0; mf < 10; ++mf) {
            if (wmbase + mf * 16 < rows) {
#pragma unroll
                for (int nf = 0; nf < 4; ++nf)
                    acc[mf][nf] = __builtin_amdgcn_mfma_f32_16x16x32_bf16(
                        a[mf], bC[nf], acc[mf][nf], 0, 0, 0);
            }
        }
        __builtin_amdgcn_s_setprio(0);

        // kk1: reads then 40 MFMA (reads drain under kk0's MFMAs via counted lgkm)
#pragma unroll
        for (int nf = 0; nf < 4; ++nf)
            bC[nf] = *(const short8*)(Acur + bB1 + nf * 2048);
#pragma unroll
        for (int i = 0; i < 10; ++i)
            a[i] = *(const short8*)(Acur + aB1 + i * 2048);
        __builtin_amdgcn_s_setprio(1);
#pragma unroll
        for (int mf = 0; mf < 10; ++mf) {
            if (wmbase + mf * 16 < rows) {
#pragma unroll
                for (int nf = 0; nf < 4; ++nf)
                    acc[mf][nf] = __builtin_amdgcn_mfma_f32_16x16x32_bf16(
                        a[mf], bC[nf], acc[mf][nf], 0, 0, 0);
            }
        }
        __builtin_amdgcn_s_setprio(0);
    }

#undef STA
#undef STB
#undef BAR

    // epilogue: tanh + W2 weighted row-sum
    float w2v[4], b1v[4];
#pragma unroll
    for (int nf = 0; nf < 4; ++nf) {
        int h = h0 + wn * 64 + nf * 16 + l15;
        w2v[nf] = w2[k * H_N + h];
        b1v[nf] = b1[k * H_N + h];
    }
#pragma unroll
    for (int mf = 0; mf < 10; ++mf) {
        float rs[4] = {0.f, 0.f, 0.f, 0.f};
#pragma unroll
        for (int nf = 0; nf < 4; ++nf) {
#pragma unroll
            for (int r = 0; r < 4; ++r)
                rs[r] += fast_tanh(acc[mf][nf][r] + b1v[nf]) * w2v[nf];
        }
#pragma unroll
        for (int r = 0; r < 4; ++r) {
            float v = rs[r];
            v += __shfl_xor(v, 8);
            v += __shfl_xor(v, 4);
            v += __shfl_xor(v, 2);
            v += __shfl_xor(v, 1);
            if (l15 == 0) pll[wn * 320 + wmbase + mf * 16 + l4 * 4 + r] = v;
        }
    }
    __syncthreads();
    if (tid < BM) {
        int m = mt * BM + tid;
        if (m < cnt) {
            u32 b = idxl[(size_t)k * B_N + m];
            atomicAdd(&out[b], pll[tid] + pll[320 + tid] + pll[640 + tid] + pll[960 + tid]);
        }
    }
}

extern "C" void kernel_launch(void* const* d_in, const int* in_sizes, int n_in,
                              void* d_out, int out_size, void* d_ws, size_t ws_size,
                              hipStream_t stream) {
    const float* x    = (const float*)d_in[0];
    const float* cent = (const float*)d_in[1];
    const float* W1   = (const float*)d_in[2];
    const float* b1   = (const float*)d_in[3];
    const float* W2   = (const float*)d_in[4];
    const float* b2   = (const float*)d_in[5];
    float* out = (float*)d_out;

    char* ws = (char*)d_ws;
    u16* xbf     = (u16*)(ws + 0);                 // 16 MB
    u16* w1t     = (u16*)(ws + 16777216);          // 32 MB
    u32* counts  = (u32*)(ws + 50331648);          // 8 strided u32 (1 KB pad)
    int* cluster = (int*)(ws + 50332672);          // 32 KB
    u32* idxl    = (u32*)(ws + 50365440);          // 256 KB

    (void)hipFuncSetAttribute((const void*)gemm_kernel,
                              hipFuncAttributeMaxDynamicSharedMemorySize, GEMM_LDS);

    // 3 dispatches: prep (fused w1t + route; zeroes counts) -> scatter -> gemm.
    hipLaunchKernelGGL(prep_kernel, dim3(6144), dim3(256), 0, stream,
                       W1, w1t, counts, x, cent, b2, xbf, cluster, out);
    hipLaunchKernelGGL(scatter_kernel, dim3(32), dim3(256), 0, stream,
                       cluster, counts, idxl);
    hipLaunchKernelGGL(gemm_kernel, dim3(8, GRID_MT), dim3(512), GEMM_LDS, stream,
                       xbf, w1t, b1, W2, idxl, counts, out);
}